// Round 16
// baseline (246.724 us; speedup 1.0000x reference)
//
#include <hip/hip_runtime.h>
#include <stdint.h>

#define TT 512
#define BB 32
#define EE 512
#define HH 2048

typedef __attribute__((ext_vector_type(8))) short short8;   // 8 x bf16 (4 VGPRs)
typedef __attribute__((ext_vector_type(4))) float f32x4;    // MFMA accumulator

// LDS geometry (in shorts)
#define XROW 528            // 512 data + 16 pad: measured 0 bank conflicts;
                            // 520 gave 8.4M conflicts. Row stride 1056 B.
#define XBUF (16 * XROW)    // one 16-t chunk buffer = 8448 shorts (16.5 KB)

static __device__ __forceinline__ float fast_exp(float x) {
    return __builtin_amdgcn_exp2f(x * 1.44269504f);
}
static __device__ __forceinline__ float fast_rcp(float x) {
    return __builtin_amdgcn_rcpf(x);
}

// Packed fp32->bf16 RNE convert: 1 instr per 2 elements.
static __device__ __forceinline__ unsigned cvtpk_bf16(float lo, float hi) {
    unsigned r;
    asm("v_cvt_pk_bf16_f32 %0, %1, %2" : "=v"(r) : "v"(lo), "v"(hi));
    return r;
}

// Async global->LDS DMA, 16 B/lane (wave-uniform LDS base + lane*16).
static __device__ __forceinline__ void load_lds16(const unsigned short* g, unsigned short* l) {
    __builtin_amdgcn_global_load_lds(
        (const __attribute__((address_space(1))) unsigned int*)(uintptr_t)g,
        (__attribute__((address_space(3))) unsigned int*)(uintptr_t)l,
        16, 0, 0);
}

// ---------------------------------------------------------------------------
// Pre-kernel (R9-verified): BW-optimal convert. Block-uniform X/W partition,
// 16 elems/thread (4 float4 loads -> 4 cvt_pk pairs -> 2 short8 stores),
// exact cover, max occupancy. One-pass W conversion here beats folding it
// into qrnn preload (R14: per-block fp32 W re-reads doubled FETCH, +18 us).
// ---------------------------------------------------------------------------
__launch_bounds__(256, 8)
__global__ void convert_inputs(const float* __restrict__ X,
                               const float* __restrict__ W,
                               unsigned short* __restrict__ Xb,
                               unsigned short* __restrict__ Wb) {
    // X: 8,388,608 elems = 2048 blocks * 4096; W: 3,145,728 = 768 blocks.
    const int bid = blockIdx.x;
    const float* src;
    unsigned short* dst;
    size_t base;
    if (bid < 2048) { src = X; dst = Xb; base = (size_t)bid * 4096; }
    else            { src = W; dst = Wb; base = (size_t)(bid - 2048) * 4096; }
    size_t j = base + (size_t)threadIdx.x * 16;

    float4 v0 = *(const float4*)(src + j);
    float4 v1 = *(const float4*)(src + j + 4);
    float4 v2 = *(const float4*)(src + j + 8);
    float4 v3 = *(const float4*)(src + j + 12);
    union { short8 s; unsigned u[4]; } o0, o1;
    o0.u[0] = cvtpk_bf16(v0.x, v0.y);
    o0.u[1] = cvtpk_bf16(v0.z, v0.w);
    o0.u[2] = cvtpk_bf16(v1.x, v1.y);
    o0.u[3] = cvtpk_bf16(v1.z, v1.w);
    o1.u[0] = cvtpk_bf16(v2.x, v2.y);
    o1.u[1] = cvtpk_bf16(v2.z, v2.w);
    o1.u[2] = cvtpk_bf16(v3.x, v3.y);
    o1.u[3] = cvtpk_bf16(v3.z, v3.w);
    *(short8*)(dst + j)     = o0.s;
    *(short8*)(dst + j + 8) = o1.s;
}

// ---------------------------------------------------------------------------
// Fused QRNN kernel — R20: EXACT R9 structure (session best, 171.6 us) with
// ONE isolated change: accumulator chains split 3x depth-8 -> 6x depth-4.
//
// Rationale: dependent same-acc MFMAs were 3 issue slots apart (~15 cyc) vs
// ~16-20 cyc MFMA latency -> ~5 cyc stall per MFMA on the critical s=0 wave
// (~100-120 cyc/region). 6 chains puts dependents 6 slots apart (~30 cyc):
// stall-free issue. +12 VGPR (100->112; +96 AGPR = 208 < 256, 2 waves/SIMD
// preserved). R4 tried this but confounded with redundant tails; this is
// the clean A/B. Numerically exact reassociation (per-chain order
// unchanged; final pair-sum commutes).
//
// R9-verified structure: K-split 2-way, 4 waves, W pinned in AGPR, X staged
// by global_load_lds DMA (double-buffered, XROW=528), rotated software
// pipeline (region ch issues MFMA(ch), runs tail(ch-1)), early exch read,
// XCD-aware block swizzle, setprio(1) around the MFMA burst, ONE
// __syncthreads per chunk.
// Hazards: (1) publish(ch) vs tail-read(ch): barrier(ch). (2) tail-read(ch)
// vs re-publish(ch+2): barrier(ch+1). (3) X buf reread/rewrite: lgkm drained
// at barrier. (4) stage(ch+1) DMA vs consume in ch+1: vmcnt drained at
// barrier(ch).
// ---------------------------------------------------------------------------
__launch_bounds__(256, 2)
__global__ void qrnn_fused(const unsigned short* __restrict__ Xb, // bf16 (T,B,E)
                           const unsigned short* __restrict__ Wb, // bf16 (3H,E)
                           const float* __restrict__ bias,        // (3H)
                           float* __restrict__ out)               // (B,H) fp32
{
    __shared__ unsigned short xlds[2 * XBUF];      // 33,792 B
    __shared__ float exch[2][2][64][12];           // 12,288 B  (total 46,080 B)

    const int tid  = threadIdx.x;
    const int wv   = tid >> 6;         // wave 0..3
    const int lane = tid & 63;
    const int q    = lane >> 4;        // quad 0..3
    const int c    = lane & 15;        // column within 16x16 tile
    const int hi   = wv >> 1;          // h-tile 0..1
    const int s    = wv & 1;           // k-half 0..1

    // XCD-aware swizzle: 2048 blocks = 8 XCDs x 4 batches x 64 h-groups.
    const int id   = blockIdx.x;       // 0..2047
    const int xcd  = id & 7;
    const int slot = id >> 3;          // 0..255 within this XCD
    const int b    = xcd * 4 + (slot >> 6);   // 4 batches per XCD
    const int hgrp = slot & 63;               // 64 h-groups per batch
    const int h    = hgrp * 32 + hi * 16 + c;

    // ---- preload W fragments (this wave's K half); pin into AGPRs ----
    // B-frag layout for 16x16x32: lane holds n = lane&15 (= h), k = q*8 + j.
    short8 wz[8], wf[8], wo[8];
    {
        const unsigned short* wzr = Wb + (size_t)h * EE            + s * 256;
        const unsigned short* wfr = Wb + (size_t)(HH + h) * EE     + s * 256;
        const unsigned short* wor = Wb + (size_t)(2 * HH + h) * EE + s * 256;
#pragma unroll
        for (int k = 0; k < 8; ++k) {
            int e0 = k * 32 + q * 8;
            wz[k] = *(const short8*)(wzr + e0);
            wf[k] = *(const short8*)(wfr + e0);
            wo[k] = *(const short8*)(wor + e0);
        }
    }
#pragma unroll
    for (int k = 0; k < 8; ++k) {
        asm volatile("" : "+a"(wz[k]), "+a"(wf[k]), "+a"(wo[k]));
    }

    const float b0 = (s == 0) ? bias[h]          : 0.0f;
    const float b1 = (s == 0) ? bias[HH + h]     : 0.0f;
    const float b2 = (s == 0) ? bias[2 * HH + h] : 0.0f;

    float carry = 0.0f;
    float vmax  = -1e30f;

    // ---- staging: wave wv owns rows wv*4 .. wv*4+3 of each 16-t chunk ----
    const unsigned short* g0 = Xb + ((size_t)(wv * 4) * BB + b) * EE + lane * 8;
    unsigned short* l0 = &xlds[(wv * 4) * XROW];

    auto stage = [&](int n, int slt) {
        const unsigned short* g = g0 + (size_t)n * (16 * BB * EE);
        unsigned short* l = l0 + slt * XBUF;
#pragma unroll
        for (int i = 0; i < 4; ++i)
            load_lds16(g + (size_t)i * (BB * EE), l + i * XROW);
    };

    // tail for one chunk's fully-summed accumulators (s==0 waves only).
    auto do_tail = [&](f32x4 az, f32x4 af, f32x4 ao) {
        float aa[4], mm[4], oo[4];
#pragma unroll
        for (int r = 0; r < 4; ++r) {
            float e2 = fast_exp(2.0f * az[r]);
            float z  = 1.0f - 2.0f * fast_rcp(e2 + 1.0f);  // tanh
            float f  = fast_rcp(1.0f + fast_exp(-af[r]));  // sigmoid
            float o  = fast_rcp(1.0f + fast_exp(-ao[r]));  // sigmoid
            aa[r] = f * z;
            mm[r] = 1.0f - f;
            oo[r] = o;
        }

        float A = aa[0], M = mm[0];
#pragma unroll
        for (int r = 1; r < 4; ++r) { A = aa[r] + mm[r] * A; M = mm[r] * M; }

        float Ap = __shfl_up(A, 16, 64), Mp = __shfl_up(M, 16, 64);
        if (q >= 1) { A = A + M * Ap; M = M * Mp; }
        Ap = __shfl_up(A, 32, 64); Mp = __shfl_up(M, 32, 64);
        if (q >= 2) { A = A + M * Ap; M = M * Mp; }
        float Ae = __shfl_up(A, 16, 64), Me = __shfl_up(M, 16, 64);
        if (q == 0) { Ae = 0.0f; Me = 1.0f; }
        float cc = Ae + Me * carry;

#pragma unroll
        for (int r = 0; r < 4; ++r) {
            cc = aa[r] + mm[r] * cc;
            vmax = fmaxf(vmax, oo[r] * cc);
        }

        float cend = A + M * carry;
        carry = __shfl(cend, 48 + c, 64);
    };

    stage(0, 0);
    __syncthreads();

    f32x4 prevz, prevf, prevo;   // MFMA results of chunk ch-1 (rotation state)

    for (int ch = 0; ch < 32; ++ch) {
        const int buf = ch & 1;
        if (ch < 31) stage(ch + 1, buf ^ 1);

        // ---- prefetch ALL A-frags for this chunk (8 back-to-back b128) ----
        const unsigned short* Abase = &xlds[buf * XBUF + c * XROW + s * 256 + q * 8];
        short8 a[8];
#pragma unroll
        for (int k = 0; k < 8; ++k)
            a[k] = *(const short8*)(Abase + k * 32);

        // ---- early exchange read for tail(ch-1) ----
        f32x4 pz, pf, po;
        if (s == 0 && ch > 0) {
            const float* e = &exch[(ch - 1) & 1][hi][lane][0];
            pz = *(const f32x4*)(e);
            pf = *(const f32x4*)(e + 4);
            po = *(const f32x4*)(e + 8);
        }

        // ---- MFMA burst: 24 MFMAs in 6 independent chains of depth 4
        //      (dependents 6 issue slots apart -> stall-free); setprio(1) ----
        f32x4 az0 = {b0, b0, b0, b0}, az1 = {0.f, 0.f, 0.f, 0.f};
        f32x4 af0 = {b1, b1, b1, b1}, af1 = {0.f, 0.f, 0.f, 0.f};
        f32x4 ao0 = {b2, b2, b2, b2}, ao1 = {0.f, 0.f, 0.f, 0.f};
        __builtin_amdgcn_s_setprio(1);
#pragma unroll
        for (int k = 0; k < 8; k += 2) {
            az0 = __builtin_amdgcn_mfma_f32_16x16x32_bf16(a[k],     wz[k],     az0, 0, 0, 0);
            af0 = __builtin_amdgcn_mfma_f32_16x16x32_bf16(a[k],     wf[k],     af0, 0, 0, 0);
            ao0 = __builtin_amdgcn_mfma_f32_16x16x32_bf16(a[k],     wo[k],     ao0, 0, 0, 0);
            az1 = __builtin_amdgcn_mfma_f32_16x16x32_bf16(a[k + 1], wz[k + 1], az1, 0, 0, 0);
            af1 = __builtin_amdgcn_mfma_f32_16x16x32_bf16(a[k + 1], wf[k + 1], af1, 0, 0, 0);
            ao1 = __builtin_amdgcn_mfma_f32_16x16x32_bf16(a[k + 1], wo[k + 1], ao1, 0, 0, 0);
        }
        __builtin_amdgcn_s_setprio(0);
        f32x4 az = az0 + az1, af = af0 + af1, ao = ao0 + ao1;

        // ---- s=1 publishes THIS chunk's partials ----
        if (s == 1) {
            float* e = &exch[ch & 1][hi][lane][0];
            *(f32x4*)(e)     = az;
            *(f32x4*)(e + 4) = af;
            *(f32x4*)(e + 8) = ao;
        }

        // ---- tail(ch-1): pure VALU on prev* + p*; overlaps matrix pipe ----
        if (s == 0 && ch > 0) {
            do_tail(prevz + pz, prevf + pf, prevo + po);
        }

        prevz = az; prevf = af; prevo = ao;

        __syncthreads();   // the ONE barrier per chunk (hazards 1-4)
    }

    // ---- epilogue: tail(31) ----
    if (s == 0) {
        const float* e = &exch[31 & 1][hi][lane][0];
        f32x4 pz = *(const f32x4*)(e);
        f32x4 pf = *(const f32x4*)(e + 4);
        f32x4 po = *(const f32x4*)(e + 8);
        do_tail(prevz + pz, prevf + pf, prevo + po);

        vmax = fmaxf(vmax, __shfl_xor(vmax, 16, 64));
        vmax = fmaxf(vmax, __shfl_xor(vmax, 32, 64));
        if (q == 0) out[(size_t)b * HH + h] = vmax;
    }
}

// ---------------------------------------------------------------------------
extern "C" void kernel_launch(void* const* d_in, const int* in_sizes, int n_in,
                              void* d_out, int out_size, void* d_ws, size_t ws_size,
                              hipStream_t stream) {
    const float* sent = (const float*)d_in[0];
    // d_in[1] = lengths (unused by the math)
    const float* W    = (const float*)d_in[2];
    const float* bias = (const float*)d_in[3];
    float* out        = (float*)d_out;

    const int nX = TT * BB * EE;        // 8,388,608
    unsigned short* Xb = (unsigned short*)d_ws;
    unsigned short* Wb = Xb + nX;       // 16 MiB offset, 16B-aligned

    // X: 2048 blocks, W: 768 blocks (4096 elems each, exact cover)
    convert_inputs<<<2816, 256, 0, stream>>>(sent, W, Xb, Wb);

    dim3 grid(2048);                    // 1-D: swizzled to (xcd, b, hgrp) in-kernel
    qrnn_fused<<<grid, 256, 0, stream>>>(Xb, Wb, bias, out);
}

// Round 17
// 233.972 us; speedup vs baseline: 1.0545x; 1.0545x over previous
//
#include <hip/hip_runtime.h>
#include <stdint.h>

#define TT 512
#define BB 32
#define EE 512
#define HH 2048

typedef __attribute__((ext_vector_type(8))) short short8;   // 8 x bf16 (4 VGPRs)
typedef __attribute__((ext_vector_type(4))) float f32x4;    // MFMA accumulator

// LDS geometry (in shorts)
#define XROW 528            // 512 data + 16 pad: measured 0 bank conflicts;
                            // 520 gave 8.4M conflicts. Row stride 1056 B.
#define XBUF (16 * XROW)    // one 16-t chunk buffer = 8448 shorts (16.5 KB)

static __device__ __forceinline__ float fast_exp(float x) {
    return __builtin_amdgcn_exp2f(x * 1.44269504f);
}
static __device__ __forceinline__ float fast_rcp(float x) {
    return __builtin_amdgcn_rcpf(x);
}

// Packed fp32->bf16 RNE convert: 1 instr per 2 elements.
static __device__ __forceinline__ unsigned cvtpk_bf16(float lo, float hi) {
    unsigned r;
    asm("v_cvt_pk_bf16_f32 %0, %1, %2" : "=v"(r) : "v"(lo), "v"(hi));
    return r;
}

// Async global->LDS DMA, 16 B/lane (wave-uniform LDS base + lane*16).
static __device__ __forceinline__ void load_lds16(const unsigned short* g, unsigned short* l) {
    __builtin_amdgcn_global_load_lds(
        (const __attribute__((address_space(1))) unsigned int*)(uintptr_t)g,
        (__attribute__((address_space(3))) unsigned int*)(uintptr_t)l,
        16, 0, 0);
}

// ---------------------------------------------------------------------------
// Pre-kernel (R9-verified, SESSION FINAL): BW-optimal convert. Block-uniform
// X/W partition, 16 elems/thread (4 float4 loads -> 4 cvt_pk pairs -> 2
// short8 stores), exact cover, max occupancy. One-pass W conversion beats
// folding into qrnn preload (R14: per-block fp32 W re-reads doubled FETCH).
// ---------------------------------------------------------------------------
__launch_bounds__(256, 8)
__global__ void convert_inputs(const float* __restrict__ X,
                               const float* __restrict__ W,
                               unsigned short* __restrict__ Xb,
                               unsigned short* __restrict__ Wb) {
    // X: 8,388,608 elems = 2048 blocks * 4096; W: 3,145,728 = 768 blocks.
    const int bid = blockIdx.x;
    const float* src;
    unsigned short* dst;
    size_t base;
    if (bid < 2048) { src = X; dst = Xb; base = (size_t)bid * 4096; }
    else            { src = W; dst = Wb; base = (size_t)(bid - 2048) * 4096; }
    size_t j = base + (size_t)threadIdx.x * 16;

    float4 v0 = *(const float4*)(src + j);
    float4 v1 = *(const float4*)(src + j + 4);
    float4 v2 = *(const float4*)(src + j + 8);
    float4 v3 = *(const float4*)(src + j + 12);
    union { short8 s; unsigned u[4]; } o0, o1;
    o0.u[0] = cvtpk_bf16(v0.x, v0.y);
    o0.u[1] = cvtpk_bf16(v0.z, v0.w);
    o0.u[2] = cvtpk_bf16(v1.x, v1.y);
    o0.u[3] = cvtpk_bf16(v1.z, v1.w);
    o1.u[0] = cvtpk_bf16(v2.x, v2.y);
    o1.u[1] = cvtpk_bf16(v2.z, v2.w);
    o1.u[2] = cvtpk_bf16(v3.x, v3.y);
    o1.u[3] = cvtpk_bf16(v3.z, v3.w);
    *(short8*)(dst + j)     = o0.s;
    *(short8*)(dst + j + 8) = o1.s;
}

// ---------------------------------------------------------------------------
// Fused QRNN kernel — SESSION FINAL (R9 structure; measured 171.6 us qrnn /
// 234.7 us total in R9, reproduced 170.6-172.5 in R15 — the minimum across
// 14 isolated structural probes R1-R16).
//
// Structure: K-split 2-way, 4 waves (2 h-tiles x 2 k-halves), W pinned in
// AGPR (96/wave), X staged by global_load_lds DMA (double-buffered,
// XROW=528, 0 bank conflicts), rotated software pipeline (region ch issues
// MFMA(ch), runs tail(ch-1) — matrix/VALU overlap), early exch read,
// XCD-aware block swizzle (4 b's/XCD -> X slab L2-resident), setprio(1)
// around the MFMA burst, ONE __syncthreads per chunk.
//
// Falsified levers (each isolated, all neutral or worse): counted vmcnt
// depth-2 (R3), redundant tails (R4), 4-way K-split 2x occupancy (R5),
// act/scan tail split (R6), direct-from-global A (R7), gate-split
// specialization (R10), 16-barrier 32t regions (R11), hierarchical scan
// (R12), tail-role rotation (R13), W-fold into preload (R14), 6-chain
// accumulator split (R16: +24 VALU/region pair-sums cost more than the
// already-covered MFMA stall). No pipe saturated; the residual is
// convoy/issue serialization of a 32-step barrier-paced recurrence at
// 2 blocks/CU (register-bound).
//
// Hazards: (1) publish(ch) vs tail-read(ch): barrier(ch). (2) tail-read(ch)
// vs re-publish(ch+2): barrier(ch+1). (3) X buf reread/rewrite: lgkm drained
// at barrier. (4) stage(ch+1) DMA vs consume in ch+1: vmcnt drained at
// barrier(ch).
// ---------------------------------------------------------------------------
__launch_bounds__(256, 2)
__global__ void qrnn_fused(const unsigned short* __restrict__ Xb, // bf16 (T,B,E)
                           const unsigned short* __restrict__ Wb, // bf16 (3H,E)
                           const float* __restrict__ bias,        // (3H)
                           float* __restrict__ out)               // (B,H) fp32
{
    __shared__ unsigned short xlds[2 * XBUF];      // 33,792 B
    __shared__ float exch[2][2][64][12];           // 12,288 B  (total 46,080 B)

    const int tid  = threadIdx.x;
    const int wv   = tid >> 6;         // wave 0..3
    const int lane = tid & 63;
    const int q    = lane >> 4;        // quad 0..3
    const int c    = lane & 15;        // column within 16x16 tile
    const int hi   = wv >> 1;          // h-tile 0..1
    const int s    = wv & 1;           // k-half 0..1

    // XCD-aware swizzle: 2048 blocks = 8 XCDs x 4 batches x 64 h-groups.
    const int id   = blockIdx.x;       // 0..2047
    const int xcd  = id & 7;
    const int slot = id >> 3;          // 0..255 within this XCD
    const int b    = xcd * 4 + (slot >> 6);   // 4 batches per XCD
    const int hgrp = slot & 63;               // 64 h-groups per batch
    const int h    = hgrp * 32 + hi * 16 + c;

    // ---- preload W fragments (this wave's K half); pin into AGPRs ----
    // B-frag layout for 16x16x32: lane holds n = lane&15 (= h), k = q*8 + j.
    short8 wz[8], wf[8], wo[8];
    {
        const unsigned short* wzr = Wb + (size_t)h * EE            + s * 256;
        const unsigned short* wfr = Wb + (size_t)(HH + h) * EE     + s * 256;
        const unsigned short* wor = Wb + (size_t)(2 * HH + h) * EE + s * 256;
#pragma unroll
        for (int k = 0; k < 8; ++k) {
            int e0 = k * 32 + q * 8;
            wz[k] = *(const short8*)(wzr + e0);
            wf[k] = *(const short8*)(wfr + e0);
            wo[k] = *(const short8*)(wor + e0);
        }
    }
#pragma unroll
    for (int k = 0; k < 8; ++k) {
        asm volatile("" : "+a"(wz[k]), "+a"(wf[k]), "+a"(wo[k]));
    }

    const float b0 = (s == 0) ? bias[h]          : 0.0f;
    const float b1 = (s == 0) ? bias[HH + h]     : 0.0f;
    const float b2 = (s == 0) ? bias[2 * HH + h] : 0.0f;

    float carry = 0.0f;
    float vmax  = -1e30f;

    // ---- staging: wave wv owns rows wv*4 .. wv*4+3 of each 16-t chunk ----
    const unsigned short* g0 = Xb + ((size_t)(wv * 4) * BB + b) * EE + lane * 8;
    unsigned short* l0 = &xlds[(wv * 4) * XROW];

    auto stage = [&](int n, int slt) {
        const unsigned short* g = g0 + (size_t)n * (16 * BB * EE);
        unsigned short* l = l0 + slt * XBUF;
#pragma unroll
        for (int i = 0; i < 4; ++i)
            load_lds16(g + (size_t)i * (BB * EE), l + i * XROW);
    };

    // tail for one chunk's fully-summed accumulators (s==0 waves only).
    auto do_tail = [&](f32x4 az, f32x4 af, f32x4 ao) {
        float aa[4], mm[4], oo[4];
#pragma unroll
        for (int r = 0; r < 4; ++r) {
            float e2 = fast_exp(2.0f * az[r]);
            float z  = 1.0f - 2.0f * fast_rcp(e2 + 1.0f);  // tanh
            float f  = fast_rcp(1.0f + fast_exp(-af[r]));  // sigmoid
            float o  = fast_rcp(1.0f + fast_exp(-ao[r]));  // sigmoid
            aa[r] = f * z;
            mm[r] = 1.0f - f;
            oo[r] = o;
        }

        float A = aa[0], M = mm[0];
#pragma unroll
        for (int r = 1; r < 4; ++r) { A = aa[r] + mm[r] * A; M = mm[r] * M; }

        float Ap = __shfl_up(A, 16, 64), Mp = __shfl_up(M, 16, 64);
        if (q >= 1) { A = A + M * Ap; M = M * Mp; }
        Ap = __shfl_up(A, 32, 64); Mp = __shfl_up(M, 32, 64);
        if (q >= 2) { A = A + M * Ap; M = M * Mp; }
        float Ae = __shfl_up(A, 16, 64), Me = __shfl_up(M, 16, 64);
        if (q == 0) { Ae = 0.0f; Me = 1.0f; }
        float cc = Ae + Me * carry;

#pragma unroll
        for (int r = 0; r < 4; ++r) {
            cc = aa[r] + mm[r] * cc;
            vmax = fmaxf(vmax, oo[r] * cc);
        }

        float cend = A + M * carry;
        carry = __shfl(cend, 48 + c, 64);
    };

    stage(0, 0);
    __syncthreads();

    f32x4 prevz, prevf, prevo;   // MFMA results of chunk ch-1 (rotation state)

    for (int ch = 0; ch < 32; ++ch) {
        const int buf = ch & 1;
        if (ch < 31) stage(ch + 1, buf ^ 1);

        // ---- prefetch ALL A-frags for this chunk (8 back-to-back b128) ----
        const unsigned short* Abase = &xlds[buf * XBUF + c * XROW + s * 256 + q * 8];
        short8 a[8];
#pragma unroll
        for (int k = 0; k < 8; ++k)
            a[k] = *(const short8*)(Abase + k * 32);

        // ---- early exchange read for tail(ch-1) ----
        f32x4 pz, pf, po;
        if (s == 0 && ch > 0) {
            const float* e = &exch[(ch - 1) & 1][hi][lane][0];
            pz = *(const f32x4*)(e);
            pf = *(const f32x4*)(e + 4);
            po = *(const f32x4*)(e + 8);
        }

        // ---- MFMA burst: 24 MFMAs, 3 independent chains; setprio(1) ----
        f32x4 az = {b0, b0, b0, b0};
        f32x4 af = {b1, b1, b1, b1};
        f32x4 ao = {b2, b2, b2, b2};
        __builtin_amdgcn_s_setprio(1);
#pragma unroll
        for (int k = 0; k < 8; ++k) {
            az = __builtin_amdgcn_mfma_f32_16x16x32_bf16(a[k], wz[k], az, 0, 0, 0);
            af = __builtin_amdgcn_mfma_f32_16x16x32_bf16(a[k], wf[k], af, 0, 0, 0);
            ao = __builtin_amdgcn_mfma_f32_16x16x32_bf16(a[k], wo[k], ao, 0, 0, 0);
        }
        __builtin_amdgcn_s_setprio(0);

        // ---- s=1 publishes THIS chunk's partials ----
        if (s == 1) {
            float* e = &exch[ch & 1][hi][lane][0];
            *(f32x4*)(e)     = az;
            *(f32x4*)(e + 4) = af;
            *(f32x4*)(e + 8) = ao;
        }

        // ---- tail(ch-1): pure VALU on prev* + p*; overlaps matrix pipe ----
        if (s == 0 && ch > 0) {
            do_tail(prevz + pz, prevf + pf, prevo + po);
        }

        prevz = az; prevf = af; prevo = ao;

        __syncthreads();   // the ONE barrier per chunk (hazards 1-4)
    }

    // ---- epilogue: tail(31) ----
    if (s == 0) {
        const float* e = &exch[31 & 1][hi][lane][0];
        f32x4 pz = *(const f32x4*)(e);
        f32x4 pf = *(const f32x4*)(e + 4);
        f32x4 po = *(const f32x4*)(e + 8);
        do_tail(prevz + pz, prevf + pf, prevo + po);

        vmax = fmaxf(vmax, __shfl_xor(vmax, 16, 64));
        vmax = fmaxf(vmax, __shfl_xor(vmax, 32, 64));
        if (q == 0) out[(size_t)b * HH + h] = vmax;
    }
}

// ---------------------------------------------------------------------------
extern "C" void kernel_launch(void* const* d_in, const int* in_sizes, int n_in,
                              void* d_out, int out_size, void* d_ws, size_t ws_size,
                              hipStream_t stream) {
    const float* sent = (const float*)d_in[0];
    // d_in[1] = lengths (unused by the math)
    const float* W    = (const float*)d_in[2];
    const float* bias = (const float*)d_in[3];
    float* out        = (float*)d_out;

    const int nX = TT * BB * EE;        // 8,388,608
    unsigned short* Xb = (unsigned short*)d_ws;
    unsigned short* Wb = Xb + nX;       // 16 MiB offset, 16B-aligned

    // X: 2048 blocks, W: 768 blocks (4096 elems each, exact cover)
    convert_inputs<<<2816, 256, 0, stream>>>(sent, W, Xb, Wb);

    dim3 grid(2048);                    // 1-D: swizzled to (xcd, b, hgrp) in-kernel
    qrnn_fused<<<grid, 256, 0, stream>>>(Xb, Wb, bias, out);
}